// Round 1
// baseline (101.466 us; speedup 1.0000x reference)
//
#include <hip/hip_runtime.h>

// One thread per batch element. 4-qubit statevector (16 complex = 32 floats)
// lives entirely in registers. All gate loops fully unrolled so bit masks are
// compile-time constants (no divergence). Params gathered via float4 loads
// (192 B per param block, 16B-aligned).

struct c32 { float x, y; };

__device__ __forceinline__ c32 cmul(c32 a, c32 b) {
    return { a.x * b.x - a.y * b.y, a.x * b.y + a.y * b.x };
}
__device__ __forceinline__ c32 cadd(c32 a, c32 b) { return { a.x + b.x, a.y + b.y }; }

// PennyLane Rot(phi, theta, omega) = RZ(omega) RY(theta) RZ(phi)
__device__ __forceinline__ void make_rot(float phi, float th, float om,
                                         c32& m00, c32& m01, c32& m10, c32& m11) {
    float st, ct;
    __sincosf(0.5f * th, &st, &ct);
    float sp_, cp_;
    __sincosf(-0.5f * (phi + om), &sp_, &cp_);   // ep = exp(-0.5i(phi+omega))
    float sm_, cm_;
    __sincosf(-0.5f * (phi - om), &sm_, &cm_);   // em = exp(-0.5i(phi-omega))
    // m00 = ep*c ; m01 = -conj(em)*s ; m10 = em*s ; m11 = conj(ep)*c
    m00 = {  cp_ * ct,  sp_ * ct };
    m01 = { -cm_ * st,  sm_ * st };
    m10 = {  cm_ * st,  sm_ * st };
    m11 = {  cp_ * ct, -sp_ * ct };
}

__device__ __forceinline__ void load48(float* dst, const float* __restrict__ src) {
    const float4* s4 = reinterpret_cast<const float4*>(src);
    float4* d4 = reinterpret_cast<float4*>(dst);
#pragma unroll
    for (int i = 0; i < 12; ++i) d4[i] = s4[i];
}

// Apply one variational block: layer 0 = Rot on each qubit; layers 1..3 =
// CRot(control=q, target=(q+off)%4) for off = 1,2,3.  p: 48 floats [4][4][3].
__device__ __forceinline__ void apply_block(c32* s, const float* p) {
#pragma unroll
    for (int q = 0; q < 4; ++q) {
        c32 m00, m01, m10, m11;
        make_rot(p[q * 3 + 0], p[q * 3 + 1], p[q * 3 + 2], m00, m01, m10, m11);
        const int tmask = 1 << (3 - q);
#pragma unroll
        for (int i = 0; i < 16; ++i) {
            if ((i & tmask) == 0) {
                c32 a = s[i], b = s[i | tmask];
                s[i]         = cadd(cmul(m00, a), cmul(m01, b));
                s[i | tmask] = cadd(cmul(m10, a), cmul(m11, b));
            }
        }
    }
#pragma unroll
    for (int off = 1; off <= 3; ++off) {
#pragma unroll
        for (int q = 0; q < 4; ++q) {
            const int pi = (off * 4 + q) * 3;
            c32 m00, m01, m10, m11;
            make_rot(p[pi + 0], p[pi + 1], p[pi + 2], m00, m01, m10, m11);
            const int tq = (q + off) & 3;
            const int cmask = 1 << (3 - q);
            const int tmask = 1 << (3 - tq);
#pragma unroll
            for (int i = 0; i < 16; ++i) {
                if ((i & cmask) != 0 && (i & tmask) == 0) {
                    c32 a = s[i], b = s[i | tmask];
                    s[i]         = cadd(cmul(m00, a), cmul(m01, b));
                    s[i | tmask] = cadd(cmul(m10, a), cmul(m11, b));
                }
            }
        }
    }
}

__global__ __launch_bounds__(256) void qkge_kernel(
    const float* __restrict__ ent, const float* __restrict__ rel,
    const int* __restrict__ h, const int* __restrict__ r, const int* __restrict__ t,
    float* __restrict__ out, int B) {
    const int b = blockIdx.x * blockDim.x + threadIdx.x;
    if (b >= B) return;

    float pbuf[48];

    // sp = block(block(s0, entity[h]), relation[r])
    c32 sp[16];
#pragma unroll
    for (int i = 0; i < 16; ++i) sp[i] = { 0.25f, 0.0f };  // H^4 |0000>
    load48(pbuf, ent + (long long)h[b] * 48);
    apply_block(sp, pbuf);
    load48(pbuf, rel + (long long)r[b] * 48);
    apply_block(sp, pbuf);

    // eo = block(s0, entity[t])
    c32 eo[16];
#pragma unroll
    for (int i = 0; i < 16; ++i) eo[i] = { 0.25f, 0.0f };
    load48(pbuf, ent + (long long)t[b] * 48);
    apply_block(eo, pbuf);

    // Re(<eo|sp>) = sum eo.x*sp.x + eo.y*sp.y
    float acc = 0.0f;
#pragma unroll
    for (int i = 0; i < 16; ++i) acc += eo[i].x * sp[i].x + eo[i].y * sp[i].y;
    out[b] = acc;
}

extern "C" void kernel_launch(void* const* d_in, const int* in_sizes, int n_in,
                              void* d_out, int out_size, void* d_ws, size_t ws_size,
                              hipStream_t stream) {
    const float* ent = (const float*)d_in[0];
    const float* rel = (const float*)d_in[1];
    const int*   h   = (const int*)d_in[2];
    const int*   r   = (const int*)d_in[3];
    const int*   t   = (const int*)d_in[4];
    float* out = (float*)d_out;
    const int B = in_sizes[2];

    const int block = 256;
    const int grid = (B + block - 1) / block;
    qkge_kernel<<<grid, block, 0, stream>>>(ent, rel, h, r, t, out, B);
}

// Round 2
// 99.778 us; speedup vs baseline: 1.0169x; 1.0169x over previous
//
#include <hip/hip_runtime.h>

// Three-phase decomposition exploiting batch redundancy:
//   K1: per-entity  state_e = block(s0, ent[e])         (E=100k, coalesced)
//   K2: per-relation 16 precomputed 2x2 gate matrices   (R=1k, tiny)
//   K3: per batch element: gather state_h, apply relation block via
//       precomputed matrices (no sincos), gather state_t, dot.      (B=131k)

struct c32 { float x, y; };

__device__ __forceinline__ c32 cmul(c32 a, c32 b) {
    return { a.x * b.x - a.y * b.y, a.x * b.y + a.y * b.x };
}
__device__ __forceinline__ c32 cadd(c32 a, c32 b) { return { a.x + b.x, a.y + b.y }; }

// PennyLane Rot(phi, theta, omega) = RZ(omega) RY(theta) RZ(phi)
__device__ __forceinline__ void make_rot(float phi, float th, float om,
                                         c32& m00, c32& m01, c32& m10, c32& m11) {
    float st, ct;
    __sincosf(0.5f * th, &st, &ct);
    float sp_, cp_;
    __sincosf(-0.5f * (phi + om), &sp_, &cp_);   // ep = exp(-0.5i(phi+omega))
    float sm_, cm_;
    __sincosf(-0.5f * (phi - om), &sm_, &cm_);   // em = exp(-0.5i(phi-omega))
    m00 = {  cp_ * ct,  sp_ * ct };
    m01 = { -cm_ * st,  sm_ * st };
    m10 = {  cm_ * st,  sm_ * st };
    m11 = {  cp_ * ct, -sp_ * ct };
}

// Apply full variational block (params in pbuf[48]) to state s[16].
__device__ __forceinline__ void apply_block(c32* s, const float* p) {
#pragma unroll
    for (int q = 0; q < 4; ++q) {
        c32 m00, m01, m10, m11;
        make_rot(p[q * 3 + 0], p[q * 3 + 1], p[q * 3 + 2], m00, m01, m10, m11);
        const int tmask = 1 << (3 - q);
#pragma unroll
        for (int i = 0; i < 16; ++i) {
            if ((i & tmask) == 0) {
                c32 a = s[i], b = s[i | tmask];
                s[i]         = cadd(cmul(m00, a), cmul(m01, b));
                s[i | tmask] = cadd(cmul(m10, a), cmul(m11, b));
            }
        }
    }
#pragma unroll
    for (int off = 1; off <= 3; ++off) {
#pragma unroll
        for (int q = 0; q < 4; ++q) {
            const int pi = (off * 4 + q) * 3;
            c32 m00, m01, m10, m11;
            make_rot(p[pi + 0], p[pi + 1], p[pi + 2], m00, m01, m10, m11);
            const int tq = (q + off) & 3;
            const int cmask = 1 << (3 - q);
            const int tmask = 1 << (3 - tq);
#pragma unroll
            for (int i = 0; i < 16; ++i) {
                if ((i & cmask) != 0 && (i & tmask) == 0) {
                    c32 a = s[i], b = s[i | tmask];
                    s[i]         = cadd(cmul(m00, a), cmul(m01, b));
                    s[i | tmask] = cadd(cmul(m10, a), cmul(m11, b));
                }
            }
        }
    }
}

// K1: state_e = block(H^4|0>, ent[e]) for every entity. Coalesced param reads.
__global__ __launch_bounds__(256) void k1_entity_states(
    const float* __restrict__ ent, float* __restrict__ estate, int E) {
    const int e = blockIdx.x * blockDim.x + threadIdx.x;
    if (e >= E) return;
    float pbuf[48];
    const float4* s4 = reinterpret_cast<const float4*>(ent + (long long)e * 48);
    float4* d4 = reinterpret_cast<float4*>(pbuf);
#pragma unroll
    for (int i = 0; i < 12; ++i) d4[i] = s4[i];

    c32 s[16];
#pragma unroll
    for (int i = 0; i < 16; ++i) s[i] = { 0.25f, 0.0f };
    apply_block(s, pbuf);

    float4* o4 = reinterpret_cast<float4*>(estate + (long long)e * 32);
#pragma unroll
    for (int i = 0; i < 8; ++i) {
        o4[i] = make_float4(s[2 * i].x, s[2 * i].y, s[2 * i + 1].x, s[2 * i + 1].y);
    }
}

// K2: precompute 16 gate matrices per relation. One thread per (relation, gate).
// Layout: relmat[r][g][8] = {m00.x,m00.y,m01.x,m01.y,m10.x,m10.y,m11.x,m11.y}
__global__ __launch_bounds__(256) void k2_relation_mats(
    const float* __restrict__ rel, float* __restrict__ relmat, int R) {
    const int idx = blockIdx.x * blockDim.x + threadIdx.x;
    if (idx >= R * 16) return;
    const int rr = idx >> 4, g = idx & 15;
    const float* p = rel + (long long)rr * 48 + g * 3;
    c32 m00, m01, m10, m11;
    make_rot(p[0], p[1], p[2], m00, m01, m10, m11);
    float4* o4 = reinterpret_cast<float4*>(relmat + (long long)idx * 8);
    o4[0] = make_float4(m00.x, m00.y, m01.x, m01.y);
    o4[1] = make_float4(m10.x, m10.y, m11.x, m11.y);
}

// K3: per batch element. No transcendentals; ~2.3 kflop/thread.
__global__ __launch_bounds__(256) void k3_batch(
    const float* __restrict__ estate, const float* __restrict__ relmat,
    const int* __restrict__ h, const int* __restrict__ r, const int* __restrict__ t,
    float* __restrict__ out, int B) {
    const int b = blockIdx.x * blockDim.x + threadIdx.x;
    if (b >= B) return;

    // Load state_h
    c32 sp[16];
    {
        const float4* s4 = reinterpret_cast<const float4*>(estate + (long long)h[b] * 32);
#pragma unroll
        for (int i = 0; i < 8; ++i) {
            float4 v = s4[i];
            sp[2 * i]     = { v.x, v.y };
            sp[2 * i + 1] = { v.z, v.w };
        }
    }

    // Apply relation block via precomputed matrices.
    const float4* rm4 = reinterpret_cast<const float4*>(relmat + (long long)r[b] * 128);
#pragma unroll
    for (int g = 0; g < 16; ++g) {
        float4 a4 = rm4[2 * g], b4 = rm4[2 * g + 1];
        c32 m00 = { a4.x, a4.y }, m01 = { a4.z, a4.w };
        c32 m10 = { b4.x, b4.y }, m11 = { b4.z, b4.w };
        if (g < 4) {
            const int tmask = 1 << (3 - g);
#pragma unroll
            for (int i = 0; i < 16; ++i) {
                if ((i & tmask) == 0) {
                    c32 a = sp[i], bb = sp[i | tmask];
                    sp[i]         = cadd(cmul(m00, a), cmul(m01, bb));
                    sp[i | tmask] = cadd(cmul(m10, a), cmul(m11, bb));
                }
            }
        } else {
            const int off = 1 + ((g - 4) >> 2);
            const int q = (g - 4) & 3;
            const int tq = (q + off) & 3;
            const int cmask = 1 << (3 - q);
            const int tmask = 1 << (3 - tq);
#pragma unroll
            for (int i = 0; i < 16; ++i) {
                if ((i & cmask) != 0 && (i & tmask) == 0) {
                    c32 a = sp[i], bb = sp[i | tmask];
                    sp[i]         = cadd(cmul(m00, a), cmul(m01, bb));
                    sp[i | tmask] = cadd(cmul(m10, a), cmul(m11, bb));
                }
            }
        }
    }

    // Dot with state_t: Re(<eo|sp>)
    float acc = 0.0f;
    {
        const float4* s4 = reinterpret_cast<const float4*>(estate + (long long)t[b] * 32);
#pragma unroll
        for (int i = 0; i < 8; ++i) {
            float4 v = s4[i];
            acc += v.x * sp[2 * i].x + v.y * sp[2 * i].y;
            acc += v.z * sp[2 * i + 1].x + v.w * sp[2 * i + 1].y;
        }
    }
    out[b] = acc;
}

extern "C" void kernel_launch(void* const* d_in, const int* in_sizes, int n_in,
                              void* d_out, int out_size, void* d_ws, size_t ws_size,
                              hipStream_t stream) {
    const float* ent = (const float*)d_in[0];
    const float* rel = (const float*)d_in[1];
    const int*   h   = (const int*)d_in[2];
    const int*   r   = (const int*)d_in[3];
    const int*   t   = (const int*)d_in[4];
    float* out = (float*)d_out;

    const int E = in_sizes[0] / 48;
    const int R = in_sizes[1] / 48;
    const int B = in_sizes[2];

    float* estate = (float*)d_ws;                       // E * 32 floats
    float* relmat = estate + (size_t)E * 32;            // R * 128 floats

    k2_relation_mats<<<(R * 16 + 255) / 256, 256, 0, stream>>>(rel, relmat, R);
    k1_entity_states<<<(E + 255) / 256, 256, 0, stream>>>(ent, estate, E);
    k3_batch<<<(B + 255) / 256, 256, 0, stream>>>(estate, relmat, h, r, t, out, B);
}